// Round 3
// baseline (9838.413 us; speedup 1.0000x reference)
//
#include <hip/hip_runtime.h>
#include <math.h>

namespace {

constexpr int H0 = 256, W0 = 320, H1 = 128, W1 = 160, H2 = 64, W2 = 80, H3 = 32, W3 = 40;
constexpr int HW0 = H0 * W0, HW1 = H1 * W1, HW2 = H2 * W2, HW3 = H3 * W3;
constexpr int DEPTH = 48;
constexpr int NCS = DEPTH * HW0;  // channel stride inside the cost volume

// Bijective XCD-chunked remap (m204): physical b -> logical id so each XCD's
// round-robin share becomes a contiguous logical chunk (L2 halo locality).
__device__ __forceinline__ int xcd_remap(int b, int n) {
  const int q = n >> 3, r = n & 7, xcd = b & 7, i = b >> 3;
  return (xcd < r ? xcd * (q + 1) : r * (q + 1) + (xcd - r) * q) + i;
}

// ---------------------------------------------------------------------------
// GRU 3x3 same-pad conv over concat(x,h) (gate) / concat(x,r*h) (cand).
// Quad scheme: each thread owns a 2x2 output pixel quad -> 4x weight reuse.
// Weights pre-transformed to [i][o][9].
// ---------------------------------------------------------------------------
template <int CX, int CH, int COUT, int QX, int QY, int OCPT, int CHUNK,
          bool NEGX, bool CAND, int ZC, bool UNIF>
__device__ __forceinline__ void gru_conv_q(
    int bx, int by, int zg, int H, int W,
    const float* __restrict__ x, int xcs,
    const float* __restrict__ h, const float* __restrict__ rg,
    const float* __restrict__ wT, const float* __restrict__ bias,
    float* __restrict__ out, float* lds) {
  constexpr int CIN = CX + CH, TPX = 2 * QX, TPY = 2 * QY;
  constexpr int IW = TPX + 2, IH = TPY + 2;
  constexpr int NQ = QX * QY, SUBS = 256 / NQ;
  static_assert(SUBS * OCPT * ZC == COUT, "cfg");
  static_assert(CHUNK * IH * IW <= 6400, "lds");
  const int x0 = bx * TPX, y0 = by * TPY, HW = H * W, tid = threadIdx.x;
  const int q = tid % NQ, sub = tid / NQ;
  const int qx = q % QX, qy = q / QX;
  int ocb = zg * (COUT / ZC) + sub * OCPT;
  if (UNIF) ocb = __builtin_amdgcn_readfirstlane(ocb);  // sub wave-uniform when NQ==64
  float acc[OCPT][4];
#pragma unroll
  for (int j = 0; j < OCPT; j++) {
    const float bb = bias[ocb + j];
    acc[j][0] = bb; acc[j][1] = bb; acc[j][2] = bb; acc[j][3] = bb;
  }
  for (int c0 = 0; c0 < CIN; c0 += CHUNK) {
    __syncthreads();
    for (int idx = tid; idx < CHUNK * IH * IW; idx += 256) {
      const int cc = idx / (IH * IW), rr = idx % (IH * IW), yy = rr / IW, xx = rr % IW;
      const int gy = y0 + yy - 1, gx = x0 + xx - 1, c = c0 + cc;
      float v = 0.f;
      if ((unsigned)gy < (unsigned)H && (unsigned)gx < (unsigned)W) {
        if (c < CX) {
          v = x[(size_t)c * xcs + gy * W + gx];
          if (NEGX) v = -v;
        } else {
          const int p = (c - CX) * HW + gy * W + gx;
          v = h[p];
          if (CAND) v *= rg[p];  // r = first CH gate channels
        }
      }
      lds[idx] = v;
    }
    __syncthreads();
    for (int c = 0; c < CHUNK; c++) {
      float p[4][4];
      const float* lp = lds + (c * IH + 2 * qy) * IW + 2 * qx;  // even -> float2 ok
#pragma unroll
      for (int r = 0; r < 4; r++) {
        const float2 a = *(const float2*)(lp + r * IW);
        const float2 b = *(const float2*)(lp + r * IW + 2);
        p[r][0] = a.x; p[r][1] = a.y; p[r][2] = b.x; p[r][3] = b.y;
      }
#pragma unroll
      for (int j = 0; j < OCPT; j++) {
        const float* wc = wT + ((size_t)(c0 + c) * COUT + ocb + j) * 9;
#pragma unroll
        for (int ky = 0; ky < 3; ky++)
#pragma unroll
          for (int kx = 0; kx < 3; kx++) {
            const float wv = wc[ky * 3 + kx];
            acc[j][0] = fmaf(p[ky][kx],         wv, acc[j][0]);
            acc[j][1] = fmaf(p[ky][kx + 1],     wv, acc[j][1]);
            acc[j][2] = fmaf(p[ky + 1][kx],     wv, acc[j][2]);
            acc[j][3] = fmaf(p[ky + 1][kx + 1], wv, acc[j][3]);
          }
      }
    }
  }
  const int ox = x0 + 2 * qx, oy = y0 + 2 * qy;
#pragma unroll
  for (int j = 0; j < OCPT; j++) {
    const int oc = ocb + j;
#pragma unroll
    for (int py = 0; py < 2; py++)
#pragma unroll
      for (int px = 0; px < 2; px++) {
        const int opix = (oy + py) * W + ox + px;
        const float a = acc[j][py * 2 + px];
        if (!CAND) {
          out[oc * HW + opix] = 1.f / (1.f + expf(-a));
        } else {
          const float cd = tanhf(a);
          const float u = rg[(CH + oc) * HW + opix];
          const float hv = h[oc * HW + opix];
          out[oc * HW + opix] = u * hv + (1.f - u) * cd;
        }
      }
  }
}

struct GruArgs {
  const float* x;
  const float* c1; const float* c2; const float* c3;
  const float* h1; const float* h2; const float* h3; const float* h4;
  const float* g1; const float* g2; const float* g3; const float* g4;
  const float* w1; const float* b1; const float* w2; const float* b2;
  const float* w3; const float* b3; const float* w4; const float* b4;
  float* o1; float* o2; float* o3; float* o4;
};

// All 4 levels' gate convs in one launch. 320|320|320|160 = 1120 blocks.
__global__ __launch_bounds__(256) void gates_k(GruArgs a) {
  __shared__ __align__(16) float lds[6400];
  const int b = xcd_remap(blockIdx.x, 1120);
  if (b < 320) {
    gru_conv_q<8, 8, 16, 8, 8, 4, 16, true, false, 1, true>(
        b % 20, b / 20, 0, H0, W0, a.x, NCS, a.h1, nullptr, a.w1, a.b1, a.o1, lds);
  } else if (b < 640) {
    const int l = b - 320;
    gru_conv_q<16, 16, 32, 8, 8, 2, 16, false, false, 4, true>(
        l % 10, (l / 10) % 8, l / 80, H1, W1, a.c1, HW1, a.h2, nullptr, a.w2, a.b2, a.o2, lds);
  } else if (b < 960) {
    const int l = b - 640;
    gru_conv_q<32, 32, 64, 4, 4, 1, 32, false, false, 4, false>(
        l % 10, (l / 10) % 8, l / 80, H2, W2, a.c2, HW2, a.h3, nullptr, a.w3, a.b3, a.o3, lds);
  } else {
    const int l = b - 960;
    gru_conv_q<64, 64, 128, 4, 4, 1, 64, false, false, 8, false>(
        l % 5, (l / 5) % 4, l / 20, H3, W3, a.c3, HW3, a.h4, nullptr, a.w4, a.b4, a.o4, lds);
  }
}

// All 4 levels' cand convs + GRU combine. 320|160|160|80 = 720 blocks.
__global__ __launch_bounds__(256) void cands_k(GruArgs a) {
  __shared__ __align__(16) float lds[6400];
  const int b = xcd_remap(blockIdx.x, 720);
  if (b < 320) {
    gru_conv_q<8, 8, 8, 8, 8, 2, 16, true, true, 1, true>(
        b % 20, b / 20, 0, H0, W0, a.x, NCS, a.h1, a.g1, a.w1, a.b1, a.o1, lds);
  } else if (b < 480) {
    const int l = b - 320;
    gru_conv_q<16, 16, 16, 8, 8, 2, 16, false, true, 2, true>(
        l % 10, (l / 10) % 8, l / 80, H1, W1, a.c1, HW1, a.h2, a.g2, a.w2, a.b2, a.o2, lds);
  } else if (b < 640) {
    const int l = b - 480;
    gru_conv_q<32, 32, 32, 4, 4, 1, 32, false, true, 2, false>(
        l % 10, (l / 10) % 8, l / 80, H2, W2, a.c2, HW2, a.h3, a.g3, a.w3, a.b3, a.o3, lds);
  } else {
    const int l = b - 640;
    gru_conv_q<64, 64, 64, 4, 4, 1, 64, false, true, 4, false>(
        l % 5, (l / 5) % 4, l / 20, H3, W3, a.c3, HW3, a.h4, a.g4, a.w4, a.b4, a.o4, lds);
  }
}

// ---------------- stride-2 3x3 conv + ReLU, quad scheme, t-batched ---------
template <int CIN, int COUT, int QX, int QY, int OCPT, int CHUNK, bool NEG,
          int INH, int INW, int ONH, int ONW, bool UNIF>
__global__ __launch_bounds__(256) void enc_q_k(
    const float* __restrict__ in, int inCS, size_t inTS, int inSlots,
    const float* __restrict__ wT, const float* __restrict__ bias,
    float* __restrict__ out, size_t outTS, int outSlots, int t0, int n) {
  constexpr int TPX = 2 * QX, TPY = 2 * QY, IW = 2 * TPX + 1, IH = 2 * TPY + 1;
  constexpr int SX = ONW / TPX, SY = ONH / TPY, NQ = QX * QY, SUBS = 256 / NQ;
  static_assert(SUBS * OCPT == COUT, "cfg");
  __shared__ float lds[CHUNK * IH * IW];
  const int lb = xcd_remap(blockIdx.x, n);
  const int z = lb / (SX * SY), rr = lb % (SX * SY);
  const int bx = rr % SX, by = rr / SX, tt = t0 + z;
  const float* inp = in + (size_t)(tt % inSlots) * inTS;
  float* outp = out + (size_t)(tt % outSlots) * outTS;
  const int x0 = bx * TPX, y0 = by * TPY;
  const int ix0 = 2 * x0 - 1, iy0 = 2 * y0 - 1, tid = threadIdx.x;
  const int q = tid % NQ, sub = tid / NQ, qx = q % QX, qy = q / QX;
  int ocb = sub * OCPT;
  if (UNIF) ocb = __builtin_amdgcn_readfirstlane(ocb);
  float acc[OCPT][4];
#pragma unroll
  for (int j = 0; j < OCPT; j++) {
    const float bb = bias[ocb + j];
    acc[j][0] = bb; acc[j][1] = bb; acc[j][2] = bb; acc[j][3] = bb;
  }
  for (int c0 = 0; c0 < CIN; c0 += CHUNK) {
    __syncthreads();
    for (int idx = tid; idx < CHUNK * IH * IW; idx += 256) {
      const int cc = idx / (IH * IW), r2 = idx % (IH * IW), yy = r2 / IW, xx = r2 % IW;
      const int gy = iy0 + yy, gx = ix0 + xx;
      float v = 0.f;
      if ((unsigned)gy < (unsigned)INH && (unsigned)gx < (unsigned)INW)
        v = inp[(size_t)(c0 + cc) * inCS + gy * INW + gx];
      lds[idx] = NEG ? -v : v;
    }
    __syncthreads();
    for (int c = 0; c < CHUNK; c++) {
      float p[5][5];
      const float* lp = lds + (c * IH + 4 * qy) * IW + 4 * qx;
#pragma unroll
      for (int r = 0; r < 5; r++)
#pragma unroll
        for (int s = 0; s < 5; s++) p[r][s] = lp[r * IW + s];
#pragma unroll
      for (int j = 0; j < OCPT; j++) {
        const float* wc = wT + ((size_t)(c0 + c) * COUT + ocb + j) * 9;
#pragma unroll
        for (int ky = 0; ky < 3; ky++)
#pragma unroll
          for (int kx = 0; kx < 3; kx++) {
            const float wv = wc[ky * 3 + kx];
            acc[j][0] = fmaf(p[ky][kx],         wv, acc[j][0]);
            acc[j][1] = fmaf(p[ky][kx + 2],     wv, acc[j][1]);
            acc[j][2] = fmaf(p[ky + 2][kx],     wv, acc[j][2]);
            acc[j][3] = fmaf(p[ky + 2][kx + 2], wv, acc[j][3]);
          }
      }
    }
  }
  const int ox = x0 + 2 * qx, oy = y0 + 2 * qy;
#pragma unroll
  for (int j = 0; j < OCPT; j++)
#pragma unroll
    for (int py = 0; py < 2; py++)
#pragma unroll
      for (int px = 0; px < 2; px++)
        outp[((size_t)(ocb + j) * ONH + oy + py) * ONW + ox + px] =
            fmaxf(acc[j][py * 2 + px], 0.f);
}

// ------- ConvTranspose 3x3 s2 p1 op1 + ReLU, 2x2-cell threads, t-batched ---
template <int CIN, int COUT, int OCPT, bool SUM2, int INH, int INW>
__global__ __launch_bounds__(256) void convT_q_k(
    const float* __restrict__ A, size_t aTS, int aSlots,
    const float* __restrict__ B, size_t bTS, int bSlots,
    const float* __restrict__ wT, const float* __restrict__ bias,
    float* __restrict__ out, size_t oTS, int oSlots, int t0, int n) {
  constexpr int SX = (2 * INW) / 16, SY = (2 * INH) / 16, SUBS = 16;
  static_assert(SUBS * OCPT == COUT, "cfg");
  __shared__ float lds[CIN * 81];
  const int lb = xcd_remap(blockIdx.x, n);
  const int z = lb / (SX * SY), rr = lb % (SX * SY);
  const int bx = rr % SX, by = rr / SX, tt = t0 + z;
  const float* Ap = A + (size_t)(tt % aSlots) * aTS;
  const float* Bp = B + (size_t)(tt % bSlots) * bTS;
  float* outp = out + (size_t)(tt % oSlots) * oTS;
  const int x0 = bx * 16, y0 = by * 16, ix0 = x0 / 2, iy0 = y0 / 2;
  const int HWin = INH * INW, tid = threadIdx.x;
  for (int idx = tid; idx < CIN * 81; idx += 256) {
    const int c = idx / 81, r = idx % 81, yy = r / 9, xx = r % 9;
    const int gy = iy0 + yy, gx = ix0 + xx;
    float v = 0.f;
    if (gy < INH && gx < INW) {
      const int p = c * HWin + gy * INW + gx;
      v = Ap[p];
      if (SUM2) v += Bp[p];
    }
    lds[idx] = v;
  }
  __syncthreads();
  const int cb = tid % 16, sub = tid / 16;
  const int cbx = cb % 4, cby = cb / 4;
  const int ocb = sub * OCPT;
  float a00[OCPT][4], a01[OCPT][4], a10[OCPT][4], a11[OCPT][4];
#pragma unroll
  for (int j = 0; j < OCPT; j++) {
    const float bb = bias[ocb + j];
#pragma unroll
    for (int qi = 0; qi < 4; qi++) {
      a00[j][qi] = bb; a01[j][qi] = bb; a10[j][qi] = bb; a11[j][qi] = bb;
    }
  }
  for (int c = 0; c < CIN; c++) {
    float p[3][3];
    const float* ip = lds + c * 81 + (2 * cby) * 9 + 2 * cbx;
#pragma unroll
    for (int r = 0; r < 3; r++)
#pragma unroll
      for (int s = 0; s < 3; s++) p[r][s] = ip[r * 9 + s];
#pragma unroll
    for (int j = 0; j < OCPT; j++) {
      const float* wc = wT + ((size_t)c * COUT + ocb + j) * 9;
      const float w0 = wc[0], w1 = wc[1], w2 = wc[2], w3 = wc[3], w4 = wc[4];
      const float w5 = wc[5], w6 = wc[6], w7 = wc[7], w8 = wc[8];
#pragma unroll
      for (int dy = 0; dy < 2; dy++)
#pragma unroll
        for (int dx = 0; dx < 2; dx++) {
          const int qi = dy * 2 + dx;
          const float v00 = p[dy][dx], v01 = p[dy][dx + 1];
          const float v10 = p[dy + 1][dx], v11 = p[dy + 1][dx + 1];
          a00[j][qi] = fmaf(w4, v00, a00[j][qi]);
          a01[j][qi] = fmaf(w3, v00, a01[j][qi]);
          a01[j][qi] = fmaf(w5, v01, a01[j][qi]);
          a10[j][qi] = fmaf(w1, v00, a10[j][qi]);
          a10[j][qi] = fmaf(w7, v10, a10[j][qi]);
          a11[j][qi] = fmaf(w0, v00, a11[j][qi]);
          a11[j][qi] = fmaf(w2, v01, a11[j][qi]);
          a11[j][qi] = fmaf(w6, v10, a11[j][qi]);
          a11[j][qi] = fmaf(w8, v11, a11[j][qi]);
        }
    }
  }
  const int outW = 2 * INW;
#pragma unroll
  for (int j = 0; j < OCPT; j++) {
    float* op = outp + (size_t)(ocb + j) * (4 * HWin);
#pragma unroll
    for (int dy = 0; dy < 2; dy++)
#pragma unroll
      for (int dx = 0; dx < 2; dx++) {
        const int qi = dy * 2 + dx;
        const int ox = x0 + 2 * (2 * cbx + dx), oy = y0 + 2 * (2 * cby + dy);
        const int base = oy * outW + ox;
        op[base] = fmaxf(a00[j][qi], 0.f);
        op[base + 1] = fmaxf(a01[j][qi], 0.f);
        op[base + outW] = fmaxf(a10[j][qi], 0.f);
        op[base + outW + 1] = fmaxf(a11[j][qi], 0.f);
      }
  }
}

// ------- fused: u1 = relu(convT(u2 + r2)); reg = conv3x3(u1 + r1) ----------
__global__ __launch_bounds__(256) void up1out_k(
    const float* __restrict__ u2, size_t u2TS, int u2S,
    const float* __restrict__ r2, size_t r2TS, int r2S,
    const float* __restrict__ r1, size_t r1TS, int r1S,
    const float* __restrict__ wTu1, const float* __restrict__ bT,
    const float* __restrict__ wo, const float* __restrict__ bo,
    float* __restrict__ dout, int t0, int n) {
  __shared__ float ins[16 * 121];  // (u2+r2) 11x11 x16ch
  __shared__ float u1h[8 * 400];   // u1 halo tile 20x20 x8ch
  const int lb = xcd_remap(blockIdx.x, n);
  const int z = lb / 320, rr = lb % 320, bx = rr % 20, by = rr / 20;
  const int t = t0 + z;
  const float* U = u2 + (size_t)(t % u2S) * u2TS;
  const float* R2 = r2 + (size_t)(t % r2S) * r2TS;
  const float* R1 = r1 + (size_t)(t % r1S) * r1TS;
  const int x0 = bx * 16, y0 = by * 16;
  const int ix0 = x0 / 2 - 1, iy0 = y0 / 2 - 1, tid = threadIdx.x;
  for (int idx = tid; idx < 16 * 121; idx += 256) {
    const int c = idx / 121, r = idx % 121, yy = r / 11, xx = r % 11;
    const int gy = iy0 + yy, gx = ix0 + xx;
    float v = 0.f;
    if ((unsigned)gy < (unsigned)H1 && (unsigned)gx < (unsigned)W1) {
      const int p = c * HW1 + gy * W1 + gx;
      v = U[p] + R2[p];
    }
    ins[idx] = v;
  }
  __syncthreads();
  if (tid < 200) {  // 25 cellblocks x 8 out-ch; each covers 2x2 cells -> 4x4 px
    const int ch = tid / 25, cb = tid % 25, cbx = cb % 5, cby = cb / 5;
    const float bb = bT[ch];
    float A0[4], A1[4], A2[4], A3[4];
#pragma unroll
    for (int qi = 0; qi < 4; qi++) { A0[qi] = bb; A1[qi] = bb; A2[qi] = bb; A3[qi] = bb; }
    for (int ic = 0; ic < 16; ic++) {
      float p[3][3];
      const float* ip = ins + ic * 121 + (2 * cby) * 11 + 2 * cbx;
#pragma unroll
      for (int r = 0; r < 3; r++)
#pragma unroll
        for (int s = 0; s < 3; s++) p[r][s] = ip[r * 11 + s];
      const float* wc = wTu1 + ((size_t)ic * 8 + ch) * 9;
      const float w0 = wc[0], w1 = wc[1], w2 = wc[2], w3 = wc[3], w4 = wc[4];
      const float w5 = wc[5], w6 = wc[6], w7 = wc[7], w8 = wc[8];
#pragma unroll
      for (int dy = 0; dy < 2; dy++)
#pragma unroll
        for (int dx = 0; dx < 2; dx++) {
          const int qi = dy * 2 + dx;
          const float v00 = p[dy][dx], v01 = p[dy][dx + 1];
          const float v10 = p[dy + 1][dx], v11 = p[dy + 1][dx + 1];
          A0[qi] = fmaf(w4, v00, A0[qi]);
          A1[qi] = fmaf(w3, v00, A1[qi]); A1[qi] = fmaf(w5, v01, A1[qi]);
          A2[qi] = fmaf(w1, v00, A2[qi]); A2[qi] = fmaf(w7, v10, A2[qi]);
          A3[qi] = fmaf(w0, v00, A3[qi]); A3[qi] = fmaf(w2, v01, A3[qi]);
          A3[qi] = fmaf(w6, v10, A3[qi]); A3[qi] = fmaf(w8, v11, A3[qi]);
        }
    }
#pragma unroll
    for (int dy = 0; dy < 2; dy++)
#pragma unroll
      for (int dx = 0; dx < 2; dx++) {
        const int qi = dy * 2 + dx;
        float* up = u1h + ch * 400 + (2 * (2 * cby + dy)) * 20 + 2 * (2 * cbx + dx);
        up[0] = fmaxf(A0[qi], 0.f);
        up[1] = fmaxf(A1[qi], 0.f);
        up[20] = fmaxf(A2[qi], 0.f);
        up[21] = fmaxf(A3[qi], 0.f);
      }
  }
  __syncthreads();
  for (int idx = tid; idx < 8 * 400; idx += 256) {  // += r1 ; zero OOB halo
    const int c = idx / 400, r = idx % 400, hy = r / 20, hx = r % 20;
    const int gy = y0 - 2 + hy, gx = x0 - 2 + hx;
    if ((unsigned)gy < (unsigned)H0 && (unsigned)gx < (unsigned)W0)
      u1h[idx] += R1[c * HW0 + gy * W0 + gx];
    else
      u1h[idx] = 0.f;
  }
  __syncthreads();
  const int tx = tid % 16, ty = tid / 16;
  float acc = bo[0];
  for (int c = 0; c < 8; c++) {
    const float* up = u1h + c * 400 + (ty + 1) * 20 + tx + 1;
#pragma unroll
    for (int ky = 0; ky < 3; ky++)
#pragma unroll
      for (int kx = 0; kx < 3; kx++)
        acc = fmaf(up[ky * 20 + kx], wo[c * 9 + ky * 3 + kx], acc);
  }
  dout[(size_t)t * HW0 + (y0 + ty) * W0 + x0 + tx] = acc;
}

// ---------------- weight transform: [o][i][9] -> [i][o][9] -----------------
struct WT { const float* s; float* d; int O; int I; };
struct WTab { WT t[14]; };
__global__ __launch_bounds__(256) void wtrans_k(WTab a) {
  for (int ti = 0; ti < 14; ti++) {
    const int O = a.t[ti].O, I = a.t[ti].I, nn = O * I * 9;
    for (int idx = blockIdx.x * 256 + threadIdx.x; idx < nn; idx += gridDim.x * 256) {
      const int k = idx % 9, oi = idx / 9;
      const int i = oi % I, o = oi / I;
      a.t[ti].d[((size_t)i * O + o) * 9 + k] = a.t[ti].s[idx];
    }
  }
}

}  // namespace

extern "C" void kernel_launch(void* const* d_in, const int* in_sizes, int n_in,
                              void* d_out, int out_size, void* d_ws, size_t ws_size,
                              hipStream_t stream) {
  const float* vol = (const float*)d_in[0];
  const float* c1w = (const float*)d_in[1];  const float* c1b = (const float*)d_in[2];
  const float* c2w = (const float*)d_in[3];  const float* c2b = (const float*)d_in[4];
  const float* c3w = (const float*)d_in[5];  const float* c3b = (const float*)d_in[6];
  const float* u3w = (const float*)d_in[7];  const float* u3b = (const float*)d_in[8];
  const float* u2w = (const float*)d_in[9];  const float* u2b = (const float*)d_in[10];
  const float* u1w = (const float*)d_in[11]; const float* u1b = (const float*)d_in[12];
  const float* ow  = (const float*)d_in[13]; const float* ob  = (const float*)d_in[14];
  const float* g1gw = (const float*)d_in[15]; const float* g1gb = (const float*)d_in[16];
  const float* g1cw = (const float*)d_in[17]; const float* g1cb = (const float*)d_in[18];
  const float* g2gw = (const float*)d_in[19]; const float* g2gb = (const float*)d_in[20];
  const float* g2cw = (const float*)d_in[21]; const float* g2cb = (const float*)d_in[22];
  const float* g3gw = (const float*)d_in[23]; const float* g3gb = (const float*)d_in[24];
  const float* g3cw = (const float*)d_in[25]; const float* g3cb = (const float*)d_in[26];
  const float* g4gw = (const float*)d_in[27]; const float* g4gb = (const float*)d_in[28];
  const float* g4cw = (const float*)d_in[29]; const float* g4cb = (const float*)d_in[30];
  float* dout = (float*)d_out;
  (void)in_sizes; (void)n_in; (void)out_size;

  // per-t element counts
  const size_t r1Sz = 8 * HW0, r2Sz = 16 * HW1, r3Sz = 32 * HW2, r4Sz = 64 * HW3;
  const size_t c1Sz = 16 * HW1, c2Sz = 32 * HW2, c3Sz = 64 * HW3;
  const size_t g1Sz = 16 * HW0, g2Sz = 32 * HW1, g3Sz = 64 * HW2, g4Sz = 128 * HW3;
  const size_t ZB = 8 * HW0;
  const size_t rTot = r1Sz + r2Sz + r3Sz + r4Sz;
  const size_t cTot = c1Sz + c2Sz + c3Sz;
  const size_t gTot = g1Sz + g2Sz + g3Sz + g4Sz;
  const size_t uTot = 32 * HW2 + 16 * HW1;
  const size_t wTot = 342144;
  const size_t needA = (wTot + ZB + 48 * rTot + 48 * cTot + gTot) * sizeof(float);
  const size_t needB = (wTot + ZB + 2 * rTot + 48 * cTot + gTot + uTot) * sizeof(float);
  const int tier = ws_size >= needA ? 0 : (ws_size >= needB ? 1 : 2);
  const int TR = (tier == 0) ? 48 : 2;   // r-state slots
  const int TC = (tier == 2) ? 1 : 48;   // encoder-feature slots

  float* ws = (float*)d_ws;
  size_t off = 0;
  auto alloc = [&](size_t nn) { float* p = ws + off; off += nn; return p; };
  // transformed weights [i][o][9]
  float* wt_c1 = alloc(1152);   float* wt_c2 = alloc(4608);  float* wt_c3 = alloc(18432);
  float* wt_u3 = alloc(18432);  float* wt_u2 = alloc(4608);  float* wt_u1 = alloc(1152);
  float* wt_g1g = alloc(2304);  float* wt_g1c = alloc(1152);
  float* wt_g2g = alloc(9216);  float* wt_g2c = alloc(4608);
  float* wt_g3g = alloc(36864); float* wt_g3c = alloc(18432);
  float* wt_g4g = alloc(147456); float* wt_g4c = alloc(73728);
  float* zb = alloc(ZB);
  float* r1 = alloc((size_t)TR * r1Sz); float* r2 = alloc((size_t)TR * r2Sz);
  float* r3 = alloc((size_t)TR * r3Sz); float* r4 = alloc((size_t)TR * r4Sz);
  float* g1 = alloc(g1Sz); float* g2 = alloc(g2Sz);
  float* g3 = alloc(g3Sz); float* g4 = alloc(g4Sz);
  float* c1a = alloc((size_t)TC * c1Sz);
  float* c2a = alloc((size_t)TC * c2Sz);
  float* c3a = alloc((size_t)TC * c3Sz);
  float *u3a, *u2a;
  if (tier == 0) {  // decoder runs after the scan; c region is dead by then
    u3a = c1a;
    u2a = c1a + 48 * (32 * HW2);
  } else {
    u3a = alloc(32 * HW2);
    u2a = alloc(16 * HW1);
  }

  WTab wt{{{c1w, wt_c1, 16, 8},   {c2w, wt_c2, 32, 16},  {c3w, wt_c3, 64, 32},
           {u3w, wt_u3, 32, 64},  {u2w, wt_u2, 16, 32},  {u1w, wt_u1, 8, 16},
           {g1gw, wt_g1g, 16, 16}, {g1cw, wt_g1c, 8, 16},
           {g2gw, wt_g2g, 32, 32}, {g2cw, wt_g2c, 16, 32},
           {g3gw, wt_g3g, 64, 64}, {g3cw, wt_g3c, 32, 64},
           {g4gw, wt_g4g, 128, 128}, {g4cw, wt_g4c, 64, 128}}};
  wtrans_k<<<dim3(128), 256, 0, stream>>>(wt);
  hipMemsetAsync(zb, 0, ZB * sizeof(float), stream);  // t=0 GRU states

  if (tier < 2) {  // batched encoder, all 48 depths
    enc_q_k<8, 16, 8, 8, 4, 8, true, 256, 320, 128, 160, true>
        <<<dim3(3840), 256, 0, stream>>>(vol, NCS, (size_t)HW0, 48, wt_c1, c1b,
                                         c1a, c1Sz, 48, 0, 3840);
    enc_q_k<16, 32, 8, 8, 8, 8, false, 128, 160, 64, 80, true>
        <<<dim3(960), 256, 0, stream>>>(c1a, HW1, c1Sz, 48, wt_c2, c2b,
                                        c2a, c2Sz, 48, 0, 960);
    enc_q_k<32, 64, 4, 4, 4, 16, false, 64, 80, 32, 40, false>
        <<<dim3(960), 256, 0, stream>>>(c2a, HW2, c2Sz, 48, wt_c3, c3b,
                                        c3a, c3Sz, 48, 0, 960);
  }

  for (int t = 0; t < DEPTH; t++) {
    if (tier == 2) {
      enc_q_k<8, 16, 8, 8, 4, 8, true, 256, 320, 128, 160, true>
          <<<dim3(80), 256, 0, stream>>>(vol, NCS, (size_t)HW0, 48, wt_c1, c1b,
                                         c1a, c1Sz, 1, t, 80);
      enc_q_k<16, 32, 8, 8, 8, 8, false, 128, 160, 64, 80, true>
          <<<dim3(20), 256, 0, stream>>>(c1a, HW1, c1Sz, 1, wt_c2, c2b,
                                         c2a, c2Sz, 1, t, 20);
      enc_q_k<32, 64, 4, 4, 4, 16, false, 64, 80, 32, 40, false>
          <<<dim3(20), 256, 0, stream>>>(c2a, HW2, c2Sz, 1, wt_c3, c3b,
                                         c3a, c3Sz, 1, t, 20);
    }
    const float* x0p = vol + (size_t)t * HW0;
    const float* h1p = t ? r1 + (size_t)((t - 1) % TR) * r1Sz : zb;
    const float* h2p = t ? r2 + (size_t)((t - 1) % TR) * r2Sz : zb;
    const float* h3p = t ? r3 + (size_t)((t - 1) % TR) * r3Sz : zb;
    const float* h4p = t ? r4 + (size_t)((t - 1) % TR) * r4Sz : zb;
    const float* c1p = c1a + (size_t)(t % TC) * c1Sz;
    const float* c2p = c2a + (size_t)(t % TC) * c2Sz;
    const float* c3p = c3a + (size_t)(t % TC) * c3Sz;
    float* o1p = r1 + (size_t)(t % TR) * r1Sz;
    float* o2p = r2 + (size_t)(t % TR) * r2Sz;
    float* o3p = r3 + (size_t)(t % TR) * r3Sz;
    float* o4p = r4 + (size_t)(t % TR) * r4Sz;

    GruArgs ga{x0p, c1p, c2p, c3p, h1p, h2p, h3p, h4p,
               nullptr, nullptr, nullptr, nullptr,
               wt_g1g, g1gb, wt_g2g, g2gb, wt_g3g, g3gb, wt_g4g, g4gb,
               g1, g2, g3, g4};
    gates_k<<<dim3(1120), 256, 0, stream>>>(ga);
    GruArgs ca{x0p, c1p, c2p, c3p, h1p, h2p, h3p, h4p,
               g1, g2, g3, g4,
               wt_g1c, g1cb, wt_g2c, g2cb, wt_g3c, g3cb, wt_g4c, g4cb,
               o1p, o2p, o3p, o4p};
    cands_k<<<dim3(720), 256, 0, stream>>>(ca);

    if (tier > 0) {  // per-t decoder
      convT_q_k<64, 32, 2, false, 32, 40>
          <<<dim3(20), 256, 0, stream>>>(r4, r4Sz, TR, r4, 0, 1, wt_u3, u3b,
                                         u3a, (size_t)32 * HW2, 1, t, 20);
      convT_q_k<32, 16, 1, true, 64, 80>
          <<<dim3(80), 256, 0, stream>>>(u3a, (size_t)32 * HW2, 1, r3, r3Sz, TR,
                                         wt_u2, u2b, u2a, (size_t)16 * HW1, 1, t, 80);
      up1out_k<<<dim3(320), 256, 0, stream>>>(
          u2a, (size_t)16 * HW1, 1, r2, r2Sz, TR, r1, r1Sz, TR,
          wt_u1, u1b, ow, ob, dout, t, 320);
    }
  }

  if (tier == 0) {  // batched decoder over all 48 depths
    convT_q_k<64, 32, 2, false, 32, 40>
        <<<dim3(960), 256, 0, stream>>>(r4, r4Sz, 48, r4, 0, 1, wt_u3, u3b,
                                        u3a, (size_t)32 * HW2, 48, 0, 960);
    convT_q_k<32, 16, 1, true, 64, 80>
        <<<dim3(3840), 256, 0, stream>>>(u3a, (size_t)32 * HW2, 48, r3, r3Sz, 48,
                                         wt_u2, u2b, u2a, (size_t)16 * HW1, 48, 0, 3840);
    up1out_k<<<dim3(15360), 256, 0, stream>>>(
        u2a, (size_t)16 * HW1, 48, r2, r2Sz, 48, r1, r1Sz, 48,
        wt_u1, u1b, ow, ob, dout, 0, 15360);
  }
}